// Round 7
// baseline (412.489 us; speedup 1.0000x reference)
//
#include <hip/hip_runtime.h>
#include <hip/hip_bf16.h>
#include <stdint.h>

// Problem constants
#define NLAYERS 32
#define DSIZE   1024
#define OSIZE   1024
#define BATCH   32
#define SEQ     256

// ws layout (ints): [0]=ntiles; [16..272)=perm; [512 + 4*t ..]=tile{layer, rank_base, nranks, pad}
#define WS_PERM  16
#define WS_TILE  512
#define MAX_TILES 88   // sum ceil(cnt/4) <= 64 + 24 = 88
#define NSPLIT   16    // o-dim tiles of 64

typedef __attribute__((ext_vector_type(8)))  short short8;
typedef __attribute__((ext_vector_type(16))) float f32x16;

#define LDSTRIDE 72   // shorts per LDS row (64 + 8 pad; 144 B = 16B-aligned rows)
#define BK 64

// Workgroup barrier that waits ONLY on LDS ops (lgkmcnt), leaving global-memory
// prefetch loads in flight across the barrier. __syncthreads() would emit
// s_waitcnt vmcnt(0) and force-drain the prefetch (the m97-style ~full-latency
// stall per iteration). LDS correctness needs only lgkmcnt here.
static __device__ __forceinline__ void lds_barrier() {
    asm volatile("s_waitcnt lgkmcnt(0)\n\ts_barrier" ::: "memory");
}

__global__ void prep_kernel(const int* __restrict__ layer_idx, int* __restrict__ wsi) {
    __shared__ int cnt[NLAYERS];
    __shared__ int start_[NLAYERS];
    __shared__ int cursor[NLAYERS];
    const int t = threadIdx.x;
    if (t < NLAYERS) cnt[t] = 0;
    __syncthreads();
    int l = 0;
    if (t < SEQ) { l = layer_idx[t]; atomicAdd(&cnt[l], 1); }
    __syncthreads();
    if (t == 0) {
        int acc = 0;
        for (int i = 0; i < NLAYERS; ++i) { start_[i] = acc; cursor[i] = acc; acc += cnt[i]; }
    }
    __syncthreads();
    if (t < SEQ) {
        int r = atomicAdd(&cursor[l], 1);
        wsi[WS_PERM + r] = t;           // perm[rank] = s  (order within layer irrelevant)
    }
    if (t == 0) {
        int nt = 0;
        for (int i = 0; i < NLAYERS; ++i) {
            const int c = cnt[i];
            for (int j = 0; j < c; j += 4) {
                wsi[WS_TILE + nt*4 + 0] = i;
                wsi[WS_TILE + nt*4 + 1] = start_[i] + j;
                wsi[WS_TILE + nt*4 + 2] = (c - j < 4) ? (c - j) : 4;
                ++nt;
            }
        }
        wsi[0] = nt;   // 64..88
    }
}

// round-to-nearest fp32->bf16 pair pack: low16 = bf16(a), high16 = bf16(b)
static __device__ __forceinline__ unsigned pk2(float a, float b) {
    unsigned ua = __builtin_bit_cast(unsigned, a) + 0x8000u;
    unsigned ub = __builtin_bit_cast(unsigned, b) + 0x8000u;
    return __builtin_amdgcn_perm(ub, ua, 0x07060302u);  // {ua[2],ua[3],ub[2],ub[3]}
}

// Tile: 128 m-rows (4 ranks x 32 batch) x 64 o-cols, BK=64, 4 waves.
// Wave wv computes rows [32*wv, 32*wv+32) x all 64 cols -> rank roff == wv.
//
// Grid 1408 blocks, 1-D. XCD mapping (fid%8 = XCD under round-robin dispatch):
//   xcd = fid&7 owns the contiguous chunk run [xcd*nt/8, (xcd+1)*nt/8) x 16 ntiles.
// -> each XCD touches only ~1/8 of x; same-layer chunks stay co-XCD (B dedup in L2);
//    the 16 ntile blocks of a chunk are dispatch-adjacent on one XCD (A slab L2-hits).
// R6 measured: FETCH 101MB (~compulsory), bank-conflict 0. R7 attacks the residual
// latency stalls: lgkm-only barriers (prefetch uninterrupted) + 5 blocks/CU.
__global__ __launch_bounds__(256, 5) void gemm_kernel(
        const float* __restrict__ x, const float* __restrict__ wgt,
        const int* __restrict__ wsi, float* __restrict__ out) {
    const int ntiles = wsi[0];
    const int xcd = blockIdx.x & 7;
    const int idx = blockIdx.x >> 3;                    // 0..175
    const int g_lo = (xcd * ntiles) >> 3;
    const int g_hi = ((xcd + 1) * ntiles) >> 3;
    const int nblk = (g_hi - g_lo) << 4;                // chunks-in-run * 16 ntiles
    if (idx >= nblk) return;
    const int mt    = g_lo + (idx >> 4);                // chunk id
    const int ntile = idx & 15;                         // o block of 64
    const int layer     = wsi[WS_TILE + mt*4 + 0];
    const int rank_base = wsi[WS_TILE + mt*4 + 1];
    const int nranks    = wsi[WS_TILE + mt*4 + 2];

    __shared__ __align__(16) short ldsA[128 * LDSTRIDE];
    __shared__ __align__(16) short ldsB[64 * LDSTRIDE];

    const int t     = threadIdx.x;
    // ---- coalesced staging: wave = 4 rows x 16 lanes x 16B (4 x 256B segments/instr)
    const int c4    = (t & 15) * 4;   // float (== bf16-short) column within 64-wide k-slab
    const int rbase = t >> 4;         // 0..15; pass p covers row = rbase + 16*p

    bool svalid[4];
    int  sv[4];
    #pragma unroll
    for (int j = 0; j < 4; ++j) {
        svalid[j] = (j < nranks);
        sv[j] = svalid[j] ? wsi[WS_PERM + rank_base + j] : 0;
    }

    // A rows: row = rbase + 16p (p=0..7) -> rank roff = p>>1, batch b = rbase + 16*(p&1)
    const float* aptr[8];
    #pragma unroll
    for (int p = 0; p < 8; ++p) {
        const int roff = p >> 1;
        const int b    = rbase + ((p & 1) << 4);
        aptr[p] = x + (((size_t)(b * SEQ + sv[roff])) << 10) + c4;
    }
    // B rows: orow = ntile*64 + rbase + 16p (p=0..3)
    const float* bbase = wgt + (((size_t)((layer << 10) + ntile * 64 + rbase)) << 10) + c4;

    float4 ra[8], rb[4];
    auto load_step = [&](int kk) {
        #pragma unroll
        for (int p = 0; p < 8; ++p) {
            if (svalid[p >> 1]) ra[p] = *(const float4*)(aptr[p] + kk);
            else                ra[p] = make_float4(0.f, 0.f, 0.f, 0.f);
        }
        #pragma unroll
        for (int p = 0; p < 4; ++p)
            rb[p] = *(const float4*)(bbase + ((size_t)p << 14) + kk);  // +p*16 rows
    };

    // compute-side mapping
    const int lane = t & 63;
    const int wv   = t >> 6;
    const int wm   = wv * 32;         // wave row base == rank wv
    const int l31  = lane & 31;
    const int lh   = lane >> 5;

    f32x16 acc[2];
    #pragma unroll
    for (int ni = 0; ni < 2; ++ni)
        #pragma unroll
        for (int r = 0; r < 16; ++r) acc[ni][r] = 0.f;

    const short* pA0 = &ldsA[(wm + l31) * LDSTRIDE + lh * 8];
    const short* pB0 = &ldsB[l31 * LDSTRIDE + lh * 8];

    load_step(0);
    #pragma unroll 1
    for (int kk = 0; kk < DSIZE; kk += BK) {
        lds_barrier();     // previous compute done reading LDS (lgkm only)
        #pragma unroll
        for (int p = 0; p < 8; ++p) {
            const int row = rbase + 16 * p;
            uint2 va;
            va.x = pk2(ra[p].x, ra[p].y);
            va.y = pk2(ra[p].z, ra[p].w);
            *(uint2*)&ldsA[row * LDSTRIDE + c4] = va;
        }
        #pragma unroll
        for (int p = 0; p < 4; ++p) {
            const int row = rbase + 16 * p;
            uint2 vb;
            vb.x = pk2(rb[p].x, rb[p].y);
            vb.y = pk2(rb[p].z, rb[p].w);
            *(uint2*)&ldsB[row * LDSTRIDE + c4] = vb;
        }
        // issue next-slab loads NOW: registers just freed by pk2; loads remain
        // in flight across both lgkm-barriers and the MFMA phase, waited only
        // at next iteration's pk2 (per-register vmcnt).
        if (kk + BK < DSIZE) load_step(kk + BK);
        lds_barrier();     // LDS writes visible; vmem prefetch NOT drained
        #pragma unroll
        for (int sub = 0; sub < 4; ++sub) {       // 4 x (K=16) sub-steps
            short8 a0 = *(const short8*)(pA0 + sub*16);
            short8 b0 = *(const short8*)(pB0 + sub*16);
            short8 b1 = *(const short8*)(pB0 + 32*LDSTRIDE + sub*16);
            acc[0] = __builtin_amdgcn_mfma_f32_32x32x16_bf16(a0, b0, acc[0], 0, 0, 0);
            acc[1] = __builtin_amdgcn_mfma_f32_32x32x16_bf16(a0, b1, acc[1], 0, 0, 0);
        }
    }

    // epilogue: C/D layout col = lane&31, row = (reg&3) + 8*(reg>>2) + 4*(lane>>5)
    if (wv < nranks) {
        const int s = wsi[WS_PERM + rank_base + wv];
        #pragma unroll
        for (int ni = 0; ni < 2; ++ni) {
            const int ocol = ntile * 64 + ni * 32 + l31;
            #pragma unroll
            for (int r = 0; r < 16; ++r) {
                const int brow = (r & 3) + 8 * (r >> 2) + 4 * lh;  // = batch b
                out[(((size_t)(brow * SEQ + s)) << 10) + ocol] = acc[ni][r];
            }
        }
    }
}

extern "C" void kernel_launch(void* const* d_in, const int* in_sizes, int n_in,
                              void* d_out, int out_size, void* d_ws, size_t ws_size,
                              hipStream_t stream) {
    const float* x         = (const float*)d_in[0];
    const int*   layer_idx = (const int*)  d_in[1];
    const float* weight    = (const float*)d_in[2];
    float* out = (float*)d_out;
    int*   wsi = (int*)d_ws;

    prep_kernel<<<1, 256, 0, stream>>>(layer_idx, wsi);
    gemm_kernel<<<MAX_TILES * NSPLIT, 256, 0, stream>>>(x, weight, wsi, out);
}

// Round 8
// 252.266 us; speedup vs baseline: 1.6351x; 1.6351x over previous
//
#include <hip/hip_runtime.h>
#include <hip/hip_bf16.h>
#include <stdint.h>

// Problem constants
#define NLAYERS 32
#define DSIZE   1024
#define OSIZE   1024
#define BATCH   32
#define SEQ     256

// ws layout (ints): [0]=ntiles; [16..272)=perm; [512 + 4*t ..]=tile{layer, rank_base, nranks, pad}
#define WS_PERM  16
#define WS_TILE  512
#define MAX_TILES 88   // sum ceil(cnt/4) <= 64 + 24 = 88
#define NSPLIT   16    // o-dim tiles of 64

typedef __attribute__((ext_vector_type(8)))  short short8;
typedef __attribute__((ext_vector_type(16))) float f32x16;

#define LDSTRIDE 72   // shorts per LDS row (64 + 8 pad; 144 B = 16B-aligned rows)
#define BK 64

// Workgroup barrier that waits ONLY on LDS ops (lgkmcnt), leaving global-memory
// prefetch loads in flight across the barrier. __syncthreads() would emit
// s_waitcnt vmcnt(0) and force-drain the prefetch (the m97-style ~full-latency
// stall per iteration). LDS correctness needs only lgkmcnt here.
static __device__ __forceinline__ void lds_barrier() {
    asm volatile("s_waitcnt lgkmcnt(0)\n\ts_barrier" ::: "memory");
}

__global__ void prep_kernel(const int* __restrict__ layer_idx, int* __restrict__ wsi) {
    __shared__ int cnt[NLAYERS];
    __shared__ int start_[NLAYERS];
    __shared__ int cursor[NLAYERS];
    const int t = threadIdx.x;
    if (t < NLAYERS) cnt[t] = 0;
    __syncthreads();
    int l = 0;
    if (t < SEQ) { l = layer_idx[t]; atomicAdd(&cnt[l], 1); }
    __syncthreads();
    if (t == 0) {
        int acc = 0;
        for (int i = 0; i < NLAYERS; ++i) { start_[i] = acc; cursor[i] = acc; acc += cnt[i]; }
    }
    __syncthreads();
    if (t < SEQ) {
        int r = atomicAdd(&cursor[l], 1);
        wsi[WS_PERM + r] = t;           // perm[rank] = s  (order within layer irrelevant)
    }
    if (t == 0) {
        int nt = 0;
        for (int i = 0; i < NLAYERS; ++i) {
            const int c = cnt[i];
            for (int j = 0; j < c; j += 4) {
                wsi[WS_TILE + nt*4 + 0] = i;
                wsi[WS_TILE + nt*4 + 1] = start_[i] + j;
                wsi[WS_TILE + nt*4 + 2] = (c - j < 4) ? (c - j) : 4;
                ++nt;
            }
        }
        wsi[0] = nt;   // 64..88
    }
}

// round-to-nearest fp32->bf16 pair pack: low16 = bf16(a), high16 = bf16(b)
static __device__ __forceinline__ unsigned pk2(float a, float b) {
    unsigned ua = __builtin_bit_cast(unsigned, a) + 0x8000u;
    unsigned ub = __builtin_bit_cast(unsigned, b) + 0x8000u;
    return __builtin_amdgcn_perm(ub, ua, 0x07060302u);  // {ua[2],ua[3],ub[2],ub[3]}
}

// Tile: 128 m-rows (4 ranks x 32 batch) x 64 o-cols, BK=64, 4 waves.
// Wave wv computes rows [32*wv, 32*wv+32) x all 64 cols -> rank roff == wv.
//
// Grid 1408 blocks, 1-D. XCD mapping (fid%8 = XCD under round-robin dispatch):
//   xcd = fid&7 owns the contiguous chunk run [xcd*nt/8, (xcd+1)*nt/8) x 16 ntiles.
// -> each XCD touches only ~1/8 of x; same-layer chunks stay co-XCD (B dedup in L2);
//    the 16 ntile blocks of a chunk are dispatch-adjacent on one XCD (A slab L2-hits).
// R6 measured: FETCH 101MB (~compulsory), bank-conflict 0.
// R7 lesson: launch_bounds(256,5) caps waves at 512/5=102 UNIFIED regs (VGPR+AGPR
// share the file on gfx950) -> ra/rb spilled to scratch (WRITE_SIZE 420MB, 250us).
// R8: (256,4) -> cap 128 unified; need ~68 VGPR + 32 AGPR = 100 -> fits (R5
// compiled 64+64=128 at this tier spill-free). 4 blocks/CU = 16 waves/CU.
__global__ __launch_bounds__(256, 4) void gemm_kernel(
        const float* __restrict__ x, const float* __restrict__ wgt,
        const int* __restrict__ wsi, float* __restrict__ out) {
    const int ntiles = wsi[0];
    const int xcd = blockIdx.x & 7;
    const int idx = blockIdx.x >> 3;                    // 0..175
    const int g_lo = (xcd * ntiles) >> 3;
    const int g_hi = ((xcd + 1) * ntiles) >> 3;
    const int nblk = (g_hi - g_lo) << 4;                // chunks-in-run * 16 ntiles
    if (idx >= nblk) return;
    const int mt    = g_lo + (idx >> 4);                // chunk id
    const int ntile = idx & 15;                         // o block of 64
    const int layer     = wsi[WS_TILE + mt*4 + 0];
    const int rank_base = wsi[WS_TILE + mt*4 + 1];
    const int nranks    = wsi[WS_TILE + mt*4 + 2];

    __shared__ __align__(16) short ldsA[128 * LDSTRIDE];
    __shared__ __align__(16) short ldsB[64 * LDSTRIDE];

    const int t     = threadIdx.x;
    // ---- coalesced staging: wave = 4 rows x 16 lanes x 16B (4 x 256B segments/instr)
    const int c4    = (t & 15) * 4;   // float (== bf16-short) column within 64-wide k-slab
    const int rbase = t >> 4;         // 0..15; pass p covers row = rbase + 16*p

    bool svalid[4];
    int  sv[4];
    #pragma unroll
    for (int j = 0; j < 4; ++j) {
        svalid[j] = (j < nranks);
        sv[j] = svalid[j] ? wsi[WS_PERM + rank_base + j] : 0;
    }

    // A rows: row = rbase + 16p (p=0..7) -> rank roff = p>>1, batch b = rbase + 16*(p&1)
    const float* aptr[8];
    #pragma unroll
    for (int p = 0; p < 8; ++p) {
        const int roff = p >> 1;
        const int b    = rbase + ((p & 1) << 4);
        aptr[p] = x + (((size_t)(b * SEQ + sv[roff])) << 10) + c4;
    }
    // B rows: orow = ntile*64 + rbase + 16p (p=0..3)
    const float* bbase = wgt + (((size_t)((layer << 10) + ntile * 64 + rbase)) << 10) + c4;

    float4 ra[8], rb[4];
    auto load_step = [&](int kk) {
        #pragma unroll
        for (int p = 0; p < 8; ++p) {
            if (svalid[p >> 1]) ra[p] = *(const float4*)(aptr[p] + kk);
            else                ra[p] = make_float4(0.f, 0.f, 0.f, 0.f);
        }
        #pragma unroll
        for (int p = 0; p < 4; ++p)
            rb[p] = *(const float4*)(bbase + ((size_t)p << 14) + kk);  // +p*16 rows
    };

    // compute-side mapping
    const int lane = t & 63;
    const int wv   = t >> 6;
    const int wm   = wv * 32;         // wave row base == rank wv
    const int l31  = lane & 31;
    const int lh   = lane >> 5;

    f32x16 acc[2];
    #pragma unroll
    for (int ni = 0; ni < 2; ++ni)
        #pragma unroll
        for (int r = 0; r < 16; ++r) acc[ni][r] = 0.f;

    const short* pA0 = &ldsA[(wm + l31) * LDSTRIDE + lh * 8];
    const short* pB0 = &ldsB[l31 * LDSTRIDE + lh * 8];

    load_step(0);
    #pragma unroll 1
    for (int kk = 0; kk < DSIZE; kk += BK) {
        lds_barrier();     // previous compute done reading LDS (lgkm only)
        #pragma unroll
        for (int p = 0; p < 8; ++p) {
            const int row = rbase + 16 * p;
            uint2 va;
            va.x = pk2(ra[p].x, ra[p].y);
            va.y = pk2(ra[p].z, ra[p].w);
            *(uint2*)&ldsA[row * LDSTRIDE + c4] = va;
        }
        #pragma unroll
        for (int p = 0; p < 4; ++p) {
            const int row = rbase + 16 * p;
            uint2 vb;
            vb.x = pk2(rb[p].x, rb[p].y);
            vb.y = pk2(rb[p].z, rb[p].w);
            *(uint2*)&ldsB[row * LDSTRIDE + c4] = vb;
        }
        // issue next-slab loads NOW: registers just freed by pk2; loads remain
        // in flight across the lgkm-barrier and the MFMA phase, waited only
        // at next iteration's pk2 (per-register vmcnt).
        if (kk + BK < DSIZE) load_step(kk + BK);
        lds_barrier();     // LDS writes visible; vmem prefetch NOT drained
        #pragma unroll
        for (int sub = 0; sub < 4; ++sub) {       // 4 x (K=16) sub-steps
            short8 a0 = *(const short8*)(pA0 + sub*16);
            short8 b0 = *(const short8*)(pB0 + sub*16);
            short8 b1 = *(const short8*)(pB0 + 32*LDSTRIDE + sub*16);
            acc[0] = __builtin_amdgcn_mfma_f32_32x32x16_bf16(a0, b0, acc[0], 0, 0, 0);
            acc[1] = __builtin_amdgcn_mfma_f32_32x32x16_bf16(a0, b1, acc[1], 0, 0, 0);
        }
    }

    // epilogue: C/D layout col = lane&31, row = (reg&3) + 8*(reg>>2) + 4*(lane>>5)
    if (wv < nranks) {
        const int s = wsi[WS_PERM + rank_base + wv];
        #pragma unroll
        for (int ni = 0; ni < 2; ++ni) {
            const int ocol = ntile * 64 + ni * 32 + l31;
            #pragma unroll
            for (int r = 0; r < 16; ++r) {
                const int brow = (r & 3) + 8 * (r >> 2) + 4 * lh;  // = batch b
                out[(((size_t)(brow * SEQ + s)) << 10) + ocol] = acc[ni][r];
            }
        }
    }
}

extern "C" void kernel_launch(void* const* d_in, const int* in_sizes, int n_in,
                              void* d_out, int out_size, void* d_ws, size_t ws_size,
                              hipStream_t stream) {
    const float* x         = (const float*)d_in[0];
    const int*   layer_idx = (const int*)  d_in[1];
    const float* weight    = (const float*)d_in[2];
    float* out = (float*)d_out;
    int*   wsi = (int*)d_ws;

    prep_kernel<<<1, 256, 0, stream>>>(layer_idx, wsi);
    gemm_kernel<<<MAX_TILES * NSPLIT, 256, 0, stream>>>(x, weight, wsi, out);
}